// Round 1
// baseline (312.473 us; speedup 1.0000x reference)
//
#include <hip/hip_runtime.h>

// perm_inv_n: x[256,512,64] fp32 ->
//   per z (flat): cs[64] | gram[64x64] | ss[64] | cs^2[64] | (gram x cs)[64^3]
// Split into two kernels:
//   k_stats: 1 block/z, 512 threads -> cs, gram, h3, h4 (reads 33.6 MB, writes 4.6 MB)
//   k_h5:    16 blocks/z, 256 threads -> h5 = gram[bc]*cs[d] (streams 268 MB of stores,
//            16 blocks/CU so the store drain is not fed by a single low-occupancy block)
#define Z_DIM 256
#define A_DIM 512
#define B_DIM 64
#define PER_Z 266432
#define GRAM_OFF 64
#define H3_OFF 4160
#define H4_OFF 4224
#define H5_OFF 4288
#define CHUNK 128

typedef float f4v __attribute__((ext_vector_type(4)));  // native vec for nontemporal

__global__ __launch_bounds__(512) void k_stats(const float* __restrict__ x,
                                               float* __restrict__ out) {
    __shared__ float sx[2][CHUNK * B_DIM];  // 64 KB staging (one chunk per half)
    __shared__ float sg[B_DIM * B_DIM];     // 16 KB half-1 partial gram
    __shared__ float scs1[B_DIM];           // half-1 partial col sums

    const int z = blockIdx.x;
    const int t = threadIdx.x;
    const int half = t >> 8;   // 0 or 1
    const int u = t & 255;
    const int tb = u >> 4;     // 0..15 -> gram rows tb*4..tb*4+3
    const int tc = u & 15;     // 0..15 -> gram cols tc*4..tc*4+3

    const float* xz = x + (size_t)z * (A_DIM * B_DIM);
    float* oz = out + (size_t)z * PER_Z;

    float acc[4][4];
#pragma unroll
    for (int i = 0; i < 4; i++)
#pragma unroll
        for (int j = 0; j < 4; j++) acc[i][j] = 0.f;
    float cs_acc = 0.f;

    float* my_sx = sx[half];

    // Each half processes 2 chunks of 128 rows: half h takes chunks {h, h+2}.
    for (int c = 0; c < 2; c++) {
        const int a0 = (c * 2 + half) * CHUNK;
        // stage CHUNK x 64 floats per half: 2048 float4, 8 per thread, coalesced
        const float4* src = (const float4*)(xz + a0 * B_DIM);
        float4* dst = (float4*)my_sx;
#pragma unroll
        for (int i = 0; i < 8; i++) dst[u + i * 256] = src[u + i * 256];
        __syncthreads();

        for (int a = 0; a < CHUNK; a++) {
            float4 bv = *(const float4*)&my_sx[a * B_DIM + tb * 4];
            float4 cv = *(const float4*)&my_sx[a * B_DIM + tc * 4];
            float bb[4] = {bv.x, bv.y, bv.z, bv.w};
            float cc[4] = {cv.x, cv.y, cv.z, cv.w};
#pragma unroll
            for (int i = 0; i < 4; i++)
#pragma unroll
                for (int j = 0; j < 4; j++)
                    acc[i][j] = fmaf(bb[i], cc[j], acc[i][j]);
        }
        if (u < B_DIM) {  // first wave of each half: partial column sums
#pragma unroll 4
            for (int a = 0; a < CHUNK; a++) cs_acc += my_sx[a * B_DIM + u];
        }
        __syncthreads();
    }

    // --- reduce the two halves, write h1..h4 ---
    if (half) {
#pragma unroll
        for (int i = 0; i < 4; i++) {
            float4 v = make_float4(acc[i][0], acc[i][1], acc[i][2], acc[i][3]);
            *(float4*)&sg[(tb * 4 + i) * B_DIM + tc * 4] = v;
        }
        if (u < B_DIM) scs1[u] = cs_acc;
    }
    __syncthreads();
    if (!half) {
#pragma unroll
        for (int i = 0; i < 4; i++) {
            float4 p = *(const float4*)&sg[(tb * 4 + i) * B_DIM + tc * 4];
            float vv[4] = {acc[i][0] + p.x, acc[i][1] + p.y,
                           acc[i][2] + p.z, acc[i][3] + p.w};
            *(float4*)&oz[GRAM_OFF + (size_t)(tb * 4 + i) * B_DIM + tc * 4] =
                make_float4(vv[0], vv[1], vv[2], vv[3]);           // h2
            if (tb == tc) oz[H3_OFF + tb * 4 + i] = vv[i];         // h3 = diag
        }
        if (u < B_DIM) {
            float c = cs_acc + scs1[u];
            oz[u] = c;                 // h1
            oz[H4_OFF + u] = c * c;    // h4
        }
    }
}

// h5[b][c][d] = gram[b*64+c] * cs[d].  grid = 256 z * 16 slabs, 256 threads.
// Each block: slab s covers bc in [s*256, s*256+256), writes 64 KB contiguous.
__global__ __launch_bounds__(256) void k_h5(const float* __restrict__ outc,
                                            float* __restrict__ out) {
    const int z = blockIdx.x >> 4;
    const int s = blockIdx.x & 15;
    const int t = threadIdx.x;
    const int dg = t & 15;   // d-group: d = dg*4 .. dg*4+3 (fixed per thread)
    const int bq = t >> 4;   // 0..15

    const float* oz = outc + (size_t)z * PER_Z;
    const f4v c4 = *(const f4v*)&oz[dg * 4];        // cs[dg*4..+3], loaded once
    const float* gram = oz + GRAM_OFF;
    f4v* o5 = (f4v*)(out + (size_t)z * PER_Z + H5_OFF);

    const int base = s * 256 + bq;
#pragma unroll
    for (int i = 0; i < 16; i++) {
        const int bc = base + i * 16;
        const float g = gram[bc];                   // 16-lane broadcast, L1-hot
        f4v v = {g * c4.x, g * c4.y, g * c4.z, g * c4.w};
        // per wave: 64 contiguous float4 = 1 KB aligned segment
        __builtin_nontemporal_store(v, &o5[(size_t)bc * 16 + dg]);
    }
}

extern "C" void kernel_launch(void* const* d_in, const int* in_sizes, int n_in,
                              void* d_out, int out_size, void* d_ws, size_t ws_size,
                              hipStream_t stream) {
    const float* x = (const float*)d_in[0];
    float* out = (float*)d_out;
    k_stats<<<Z_DIM, 512, 0, stream>>>(x, out);
    k_h5<<<Z_DIM * 16, 256, 0, stream>>>(out, out);
}